// Round 1
// baseline (185.537 us; speedup 1.0000x reference)
//
#include <hip/hip_runtime.h>
#include <cstdint>
#include <cstddef>

// CausalSelfAttention MI355X (gfx950). fp32 I/O, bf16 MFMA compute, fp32 accum.
// B=2, T=2048, C=1024, H=16, Dh=64.
// [cast f32->bf16] -> [QKV gemm: 256x256 8-phase template (T1 XCD swizzle,
// T2 st_16x32 LDS swizzle, T3/T4 counted vmcnt, T5 setprio) with FUSED
// rmsnorm+rope epilogue on q/k and transposed-packed V stores] ->
// [flash attention (unchanged)] -> [gemm proj (m97 structure, unchanged)].
// Round-6 lesson: NEVER dynamically index register arrays. All static here.

typedef short bf16x8 __attribute__((ext_vector_type(8)));
typedef float floatx4 __attribute__((ext_vector_type(4)));
typedef unsigned short ushortx8 __attribute__((ext_vector_type(8)));
typedef unsigned short ushortx4 __attribute__((ext_vector_type(4)));
typedef unsigned int uintx2 __attribute__((ext_vector_type(2)));

#define DEVI __device__ __forceinline__

DEVI float bf2f(unsigned short u) {
    unsigned int x = ((unsigned int)u) << 16;
    return __builtin_bit_cast(float, x);
}
DEVI unsigned short f2bf(float f) {
    unsigned int u = __builtin_bit_cast(unsigned int, f);
    u += 0x7fffu + ((u >> 16) & 1u);   // RNE; finite values only
    return (unsigned short)(u >> 16);
}
// pack 2 fp32 -> 2 bf16 in one dword (round-half-up; inputs >= 0 here)
DEVI unsigned int pkbf2(float a, float b) {
    unsigned int ua = __builtin_bit_cast(unsigned int, a) + 0x8000u;
    unsigned int ub = __builtin_bit_cast(unsigned int, b) + 0x8000u;
    return __builtin_amdgcn_perm(ub, ua, 0x07060302);
}

// async global->LDS, 16B per lane; LDS dest = wave-uniform base + lane*16.
DEVI void glds16(const unsigned short* g, unsigned short* l) {
    __builtin_amdgcn_global_load_lds(
        (const __attribute__((address_space(1))) unsigned int*)g,
        (__attribute__((address_space(3))) unsigned int*)l, 16, 0, 0);
}

DEVI void cast8(unsigned short* dst, const float* src) {
    floatx4 a = *(const floatx4*)src;
    floatx4 b = *(const floatx4*)(src + 4);
    ushortx8 o;
    o[0] = f2bf(a[0]); o[1] = f2bf(a[1]); o[2] = f2bf(a[2]); o[3] = f2bf(a[3]);
    o[4] = f2bf(b[0]); o[5] = f2bf(b[1]); o[6] = f2bf(b[2]); o[7] = f2bf(b[3]);
    *(ushortx8*)dst = o;
}

// ---------------------------------------------------------------------------
__global__ __launch_bounds__(256)
void cast_inputs(const float* __restrict__ x, const float* __restrict__ wa,
                 const float* __restrict__ wp,
                 unsigned short* __restrict__ xb, unsigned short* __restrict__ wab,
                 unsigned short* __restrict__ wpb)
{
    size_t g = (size_t)blockIdx.x * 256 + threadIdx.x;
    size_t stride = (size_t)gridDim.x * 256;
    for (size_t i = g; i < (4194304 / 8); i += stride) cast8(xb  + i * 8, x  + i * 8);
    for (size_t i = g; i < (3145728 / 8); i += stride) cast8(wab + i * 8, wa + i * 8);
    for (size_t i = g; i < (1048576 / 8); i += stride) cast8(wpb + i * 8, wp + i * 8);
}

// ---------------------------------------------------------------------------
// QKV GEMM, 8-phase 256^2 template. C[M=4096,N=3072] = A[M,1024] @ B[N,1024]^T.
// 512 threads = 8 waves (2 wm x 4 wn), per-wave 128x64 output, BK=64,
// double-buffered 128 KiB LDS, st_16x32 swizzle (inverse-swz global source +
// swz ds_read; global_load_lds dest stays LINEAR per rule 21).
// Stage order per tile: B0,B1,B2,B3,A0,A2,A1,A3 (8 KiB units, 2 per phase).
// vmcnt(4) at Ph2 guarantees odd-A units of CURRENT tile (read Ph3);
// vmcnt(2) at Ph4 guarantees B+even-A units of NEXT tile (read Ph1/Ph2).
// Never vmcnt(0) in steady state; peeled LAST tile drains.
// ---------------------------------------------------------------------------
__global__ __launch_bounds__(512, 2)
void gemm_qkv_8ph(const unsigned short* __restrict__ A,
                  const unsigned short* __restrict__ B,
                  unsigned short* __restrict__ Cqk,
                  unsigned short* __restrict__ Vt)
{
    __shared__ __align__(16) unsigned short lds[2][2][256 * 64]; // [buf][A/B][..] 128KiB

    const int tid  = threadIdx.x;
    const int lane = tid & 63;
    const int w    = tid >> 6;         // 0..7
    const int wm   = w >> 2;           // 0..1 (output row half)
    const int wn   = w & 3;            // 0..3 (output col quarter = one head)
    const int quad = lane >> 4;
    const int lm   = lane & 15;

    // bijective XCD swizzle (192 blocks, 192 % 8 == 0)
    const int lin = blockIdx.y * 12 + blockIdx.x;
    const int s   = (lin & 7) * 24 + (lin >> 3);
    const int m0  = (s / 12) * 256;
    const int n0  = (s % 12) * 256;

    // staging geometry: one unit = 64 rows x 64 cols bf16 = 8KiB = 512 lanes x 16B
    const int srow = tid >> 3;                                   // 0..63
    const int scol = ((tid & 7) * 8) ^ (((tid >> 5) & 1) << 4);  // inverse st_16x32
    const int ldst = w * 512;                                    // per-wave LDS base (ushorts)

#define STG_A(u, WBi, kq) glds16(&A[(size_t)(m0 + (u) * 64 + srow) * 1024 + (kq) + scol], \
                                 &lds[WBi][0][(u) * 4096 + ldst])
#define STG_B(u, WBi, kq) glds16(&B[(size_t)(n0 + (u) * 64 + srow) * 1024 + (kq) + scol], \
                                 &lds[WBi][1][(u) * 4096 + ldst])
// swizzled read: ushort idx = (row*64 + off) ^ (((row>>2)&1)<<4)
#define RD_A(RBi, rrow, off) (*(const bf16x8*)&lds[RBi][0][(((rrow) * 64 + (off))) ^ ((((rrow) >> 2) & 1) << 4)])
#define RD_B(RBi, rrow, off) (*(const bf16x8*)&lds[RBi][1][(((rrow) * 64 + (off))) ^ ((((rrow) >> 2) & 1) << 4)])

    floatx4 acc[8][4] = {};
    bf16x8 afr[4][2];   // current m-half fragments (reloaded Ph1/Ph3)
    bf16x8 bfr[4][2];   // all 4 n-fragments (j0,1 from Ph1; j2,3 from Ph2)

#define MQ(MB, JB)                                                              \
  do {                                                                          \
    _Pragma("unroll")                                                           \
    for (int kk = 0; kk < 2; ++kk)                                              \
      _Pragma("unroll")                                                         \
      for (int mi = 0; mi < 4; ++mi)                                            \
        _Pragma("unroll")                                                       \
        for (int j2 = 0; j2 < 2; ++j2)                                          \
          acc[(MB) + mi][(JB) + j2] = __builtin_amdgcn_mfma_f32_16x16x32_bf16(  \
              afr[mi][kk], bfr[(JB) + j2][kk], acc[(MB) + mi][(JB) + j2], 0, 0, 0); \
  } while (0)

#define TILE(RBi, WBi, KT, LASTF)                                               \
  do {                                                                          \
    const int kn = ((KT) + 1) * 64;                                             \
    /* ---- Phase 1: reads A-even + B(j0,1); stage next B0,B1 ---- */           \
    _Pragma("unroll")                                                           \
    for (int kk = 0; kk < 2; ++kk) {                                            \
      _Pragma("unroll")                                                         \
      for (int mi = 0; mi < 4; ++mi)                                            \
        afr[mi][kk] = RD_A(RBi, wm * 128 + mi * 16 + lm, kk * 32 + quad * 8);   \
      _Pragma("unroll")                                                         \
      for (int j2 = 0; j2 < 2; ++j2)                                            \
        bfr[j2][kk] = RD_B(RBi, wn * 64 + j2 * 16 + lm, kk * 32 + quad * 8);    \
    }                                                                           \
    if (!(LASTF)) { STG_B(0, WBi, kn); STG_B(1, WBi, kn); }                     \
    __builtin_amdgcn_s_barrier();                                               \
    asm volatile("s_waitcnt lgkmcnt(0)" ::: "memory");                          \
    __builtin_amdgcn_s_setprio(1); MQ(0, 0); __builtin_amdgcn_s_setprio(0);     \
    __builtin_amdgcn_s_barrier();                                               \
    /* ---- Phase 2: reads B(j2,3); stage next B2,B3; vmcnt(4) ---- */          \
    _Pragma("unroll")                                                           \
    for (int kk = 0; kk < 2; ++kk)                                              \
      _Pragma("unroll")                                                         \
      for (int j2 = 0; j2 < 2; ++j2)                                            \
        bfr[2 + j2][kk] = RD_B(RBi, wn * 64 + (2 + j2) * 16 + lm, kk * 32 + quad * 8); \
    if (!(LASTF)) { STG_B(2, WBi, kn); STG_B(3, WBi, kn);                       \
                    asm volatile("s_waitcnt vmcnt(4)" ::: "memory"); }          \
    else          { asm volatile("s_waitcnt vmcnt(0)" ::: "memory"); }          \
    __builtin_amdgcn_s_barrier();                                               \
    asm volatile("s_waitcnt lgkmcnt(0)" ::: "memory");                          \
    __builtin_amdgcn_s_setprio(1); MQ(0, 2); __builtin_amdgcn_s_setprio(0);     \
    __builtin_amdgcn_s_barrier();                                               \
    /* ---- Phase 3: reads A-odd; stage next A0,A2 ---- */                      \
    _Pragma("unroll")                                                           \
    for (int kk = 0; kk < 2; ++kk)                                              \
      _Pragma("unroll")                                                         \
      for (int mi = 0; mi < 4; ++mi)                                            \
        afr[mi][kk] = RD_A(RBi, wm * 128 + 64 + mi * 16 + lm, kk * 32 + quad * 8); \
    if (!(LASTF)) { STG_A(0, WBi, kn); STG_A(2, WBi, kn); }                     \
    __builtin_amdgcn_s_barrier();                                               \
    asm volatile("s_waitcnt lgkmcnt(0)" ::: "memory");                          \
    __builtin_amdgcn_s_setprio(1); MQ(4, 2); __builtin_amdgcn_s_setprio(0);     \
    __builtin_amdgcn_s_barrier();                                               \
    /* ---- Phase 4: no reads (reuse regs); stage next A1,A3; vmcnt(2) ---- */  \
    if (!(LASTF)) { STG_A(1, WBi, kn); STG_A(3, WBi, kn);                       \
                    asm volatile("s_waitcnt vmcnt(2)" ::: "memory"); }          \
    __builtin_amdgcn_s_barrier();                                               \
    __builtin_amdgcn_s_setprio(1); MQ(4, 0); __builtin_amdgcn_s_setprio(0);     \
    __builtin_amdgcn_s_barrier();                                               \
  } while (0)

    // prologue: stage tile 0 fully (order B0..B3, A0, A2, A1, A3), counted wait
    STG_B(0, 0, 0); STG_B(1, 0, 0); STG_B(2, 0, 0); STG_B(3, 0, 0);
    STG_A(0, 0, 0); STG_A(2, 0, 0); STG_A(1, 0, 0); STG_A(3, 0, 0);
    asm volatile("s_waitcnt vmcnt(2)" ::: "memory");   // B0..B3,A0,A2 done; A1,A3 in flight
    __builtin_amdgcn_s_barrier();

    for (int kt = 0; kt < 14; kt += 2) {
        TILE(0, 1, kt, false);
        TILE(1, 0, kt + 1, false);
    }
    TILE(0, 1, 14, false);
    TILE(1, 0, 15, true);

    // -------- fused epilogue (identical math to verified m97-structure ver) --------
    const bool is_v = (n0 + wn * 64) >= 2048;   // wave-uniform; one head per wave
    if (!is_v) {
        float invf[4];
        #pragma unroll
        for (int j = 0; j < 4; ++j) {
            int d = j * 16 + lm;
            invf[j] = __expf(-(float)(d & 31) * 0.28782313662425572f); // ln(1e4)/32
        }
        #pragma unroll
        for (int mi = 0; mi < 8; ++mi) {
            float rn[4];
            #pragma unroll
            for (int r = 0; r < 4; ++r) {
                float ss = 0.0f;
                #pragma unroll
                for (int j = 0; j < 4; ++j) ss += acc[mi][j][r] * acc[mi][j][r];
                ss += __shfl_xor(ss, 1, 64);
                ss += __shfl_xor(ss, 2, 64);
                ss += __shfl_xor(ss, 4, 64);
                ss += __shfl_xor(ss, 8, 64);
                rn[r] = rsqrtf(ss * (1.0f / 64.0f) + 1.1920929e-07f);
            }
            #pragma unroll
            for (int r = 0; r < 4; ++r) {
                int row = m0 + wm * 128 + mi * 16 + quad * 4 + r;
                float t = (float)(row & 2047);
                float g = rn[r];
                #pragma unroll
                for (int j = 0; j < 4; ++j) {
                    int d = j * 16 + lm;
                    float sn, cs;
                    __sincosf(t * invf[j], &sn, &cs);
                    float v  = acc[mi][j][r] * g;
                    float vp = acc[mi][j ^ 2][r] * g;          // partner d^32
                    float sgn = (d < 32) ? -1.0f : 1.0f;       // (-x2, x1)
                    Cqk[(size_t)row * 2048 + (n0 + wn * 64 + d)] =
                        f2bf(v * cs + sgn * vp * sn);
                }
            }
        }
    } else {
        #pragma unroll
        for (int mi = 0; mi < 8; ++mi)
            #pragma unroll
            for (int j = 0; j < 4; ++j) {
                int col  = n0 + wn * 64 + j * 16 + lm;
                int row0 = m0 + wm * 128 + mi * 16 + quad * 4;
                int bq = row0 >> 11, t0 = row0 & 2047;
                ushortx4 pk;
                #pragma unroll
                for (int r = 0; r < 4; ++r) pk[r] = f2bf(acc[mi][j][r]);
                *(ushortx4*)&Vt[((size_t)(bq * 1024 + (col - 2048))) * 2048 + t0] = pk;
            }
    }
#undef TILE
#undef MQ
#undef RD_A
#undef RD_B
#undef STG_A
#undef STG_B
}

// ---------------------------------------------------------------------------
// C[M,N] = A[M,K] @ B[N,K]^T, bf16 in, fp32 accum. m97 structure: 128xBN
// tile, BK in {32,64}, global_load_lds width=16 into UNPADDED LDS.
// (Now used only for the proj GEMM, QKV_SPLIT=false.)
// ---------------------------------------------------------------------------
template <bool QKV_SPLIT, int BN, int BK>
__global__ __launch_bounds__(256)
void gemm_bt(const unsigned short* __restrict__ A, const unsigned short* __restrict__ B,
             unsigned short* __restrict__ Cqk, float* __restrict__ Cf,
             unsigned short* __restrict__ Vt, int M, int N, int K)
{
    constexpr int WCOLS = (BN == 128) ? 2 : 1;
    constexpr int WROWS = 4 / WCOLS;
    constexpr int MI    = 128 / (16 * WROWS);   // 4 (BN=128) or 2 (BN=64)
    constexpr int LPR   = BK / 8;               // lanes per LDS row (16B each)
    constexpr int RPI   = 64 / LPR;             // rows covered per glds16

    __shared__ __align__(16) unsigned short As[128 * BK];
    __shared__ __align__(16) unsigned short Bs[BN * BK];

    const int tid  = threadIdx.x;
    const int lane = tid & 63;
    const int w    = tid >> 6;
    const int wm   = w / WCOLS, wn = w % WCOLS;
    const int quad = lane >> 4;
    const int lm   = lane & 15;
    const int m0 = blockIdx.y * 128;
    const int n0 = blockIdx.x * BN;
    const int sr = lane / LPR;
    const int sc = (lane % LPR) * 8;

    floatx4 acc[MI][4] = {};

    for (int k0 = 0; k0 < K; k0 += BK) {
        __syncthreads();
        #pragma unroll
        for (int i = 0; i < 32 / RPI; ++i) {
            int r = w * 32 + i * RPI;
            glds16(&A[(size_t)(m0 + r + sr) * K + k0 + sc], &As[r * BK]);
        }
        #pragma unroll
        for (int i = 0; i < (BN / 4) / RPI; ++i) {
            int r = w * (BN / 4) + i * RPI;
            glds16(&B[(size_t)(n0 + r + sr) * K + k0 + sc], &Bs[r * BK]);
        }
        __syncthreads();

        #pragma unroll
        for (int kk = 0; kk < BK / 32; ++kk) {
            bf16x8 a[MI];
            #pragma unroll
            for (int i = 0; i < MI; ++i)
                a[i] = *(const bf16x8*)&As[(wm * (16 * MI) + i * 16 + lm) * BK + kk * 32 + quad * 8];
            #pragma unroll
            for (int j = 0; j < 4; ++j) {
                bf16x8 b = *(const bf16x8*)&Bs[(wn * 64 + j * 16 + lm) * BK + kk * 32 + quad * 8];
                #pragma unroll
                for (int i = 0; i < MI; ++i)
                    acc[i][j] = __builtin_amdgcn_mfma_f32_16x16x32_bf16(a[i], b, acc[i][j], 0, 0, 0);
            }
        }
    }

    if constexpr (QKV_SPLIT) {
        const bool is_v = (n0 + wn * 64) >= 2048;   // wave-uniform
        if (!is_v) {
            float rn[MI][4];
            #pragma unroll
            for (int i = 0; i < MI; ++i)
                #pragma unroll
                for (int r = 0; r < 4; ++r) {
                    float s = 0.0f;
                    #pragma unroll
                    for (int j = 0; j < 4; ++j) s += acc[i][j][r] * acc[i][j][r];
                    s += __shfl_xor(s, 1, 64);
                    s += __shfl_xor(s, 2, 64);
                    s += __shfl_xor(s, 4, 64);
                    s += __shfl_xor(s, 8, 64);
                    rn[i][r] = rsqrtf(s * (1.0f / 64.0f) + 1.1920929e-07f);
                }
            float invf[4];
            #pragma unroll
            for (int j = 0; j < 4; ++j) {
                int d = j * 16 + lm;
                invf[j] = __expf(-(float)(d & 31) * 0.28782313662425572f);
            }
            #pragma unroll
            for (int i = 0; i < MI; ++i)
                #pragma unroll
                for (int r = 0; r < 4; ++r) {
                    int row = m0 + wm * (16 * MI) + i * 16 + quad * 4 + r;
                    float t = (float)(row & 2047);
                    float g = rn[i][r];
                    #pragma unroll
                    for (int j = 0; j < 4; ++j) {
                        int d = j * 16 + lm;
                        float sn, cs;
                        __sincosf(t * invf[j], &sn, &cs);
                        float v  = acc[i][j][r] * g;
                        float vp = acc[i][j ^ 2][r] * g;
                        float sgn = (d < 32) ? -1.0f : 1.0f;
                        Cqk[(size_t)row * 2048 + (n0 + wn * 64 + d)] =
                            f2bf(v * cs + sgn * vp * sn);
                    }
                }
        } else {
            #pragma unroll
            for (int i = 0; i < MI; ++i)
                #pragma unroll
                for (int j = 0; j < 4; ++j) {
                    int col  = n0 + wn * 64 + j * 16 + lm;
                    int row0 = m0 + wm * (16 * MI) + i * 16 + quad * 4;
                    int bq = row0 >> 11, t0 = row0 & 2047;
                    ushortx4 pk;
                    #pragma unroll
                    for (int r = 0; r < 4; ++r) pk[r] = f2bf(acc[i][j][r]);
                    *(ushortx4*)&Vt[((size_t)(bq * 1024 + (col - 2048))) * 2048 + t0] = pk;
                }
        }
    } else {
        #pragma unroll
        for (int i = 0; i < MI; ++i)
            #pragma unroll
            for (int j = 0; j < 4; ++j) {
                int col  = n0 + wn * 64 + j * 16 + lm;
                int row0 = m0 + wm * (16 * MI) + i * 16 + quad * 4;
                #pragma unroll
                for (int r = 0; r < 4; ++r)
                    Cf[(size_t)(row0 + r) * N + col] = acc[i][j][r];
            }
    }
}

// ---------------------------------------------------------------------------
// Flash attention. Double-buffered K/V LDS, ONE __syncthreads per key-step,
// buffer parity statically unrolled (pair loop + remainder — zero dynamic
// indexing). Peeled diagonal step (masked, no staging, no trailing barrier).
// S^T via mfma(A=K, B=Q); P packed b64 to own LDS strip; row-sums via
// mfma(P, ones) in o's D-layout.
// ---------------------------------------------------------------------------
#define ATTN_STEP(KSc, VSc, KSn, VSn, KT, DG, LAST)                            \
  do {                                                                         \
    if (!(LAST)) {                                                             \
      *(ushortx8*)&(KSn)[r0 * LD + pc] = kreg0;                                \
      *(ushortx8*)&(KSn)[r1 * LD + pc] = kreg1;                                \
      *(ushortx8*)&(VSn)[r0 * LD + pc] = vreg0;                                \
      *(ushortx8*)&(VSn)[r1 * LD + pc] = vreg1;                                \
      if ((KT) + 2 <= qt) {                                                    \
        kreg0 = *(const ushortx8*)kp0; kreg1 = *(const ushortx8*)kp1;          \
        vreg0 = *(const ushortx8*)vp0; vreg1 = *(const ushortx8*)vp1;          \
        kp0 += (size_t)64 * 2048; kp1 += (size_t)64 * 2048;                    \
        vp0 += 64; vp1 += 64;                                                  \
      }                                                                        \
    }                                                                          \
    floatx4 sa[4] = {};                                                        \
    _Pragma("unroll")                                                          \
    for (int kk = 0; kk < 2; ++kk)                                             \
      _Pragma("unroll")                                                        \
      for (int j = 0; j < 4; ++j) {                                            \
        bf16x8 kf = *(const bf16x8*)&(KSc)[(j * 16 + lm) * LD + kk * 32 + quad * 8]; \
        sa[j] = __builtin_amdgcn_mfma_f32_16x16x32_bf16(kf, qf[kk], sa[j], 0, 0, 0); \
      }                                                                        \
    _Pragma("unroll")                                                          \
    for (int j = 0; j < 4; ++j) {                                              \
      float p0 = exp2f(sa[j][0] * c1 - c2);                                    \
      float p1 = exp2f(sa[j][1] * c1 - c2);                                    \
      float p2 = exp2f(sa[j][2] * c1 - c2);                                    \
      float p3 = exp2f(sa[j][3] * c1 - c2);                                    \
      if (DG) {                                                                \
        int kb = (KT) * 64 + j * 16 + quad * 4;                                \
        if (kb + 0 > qrow) p0 = 0.0f;                                          \
        if (kb + 1 > qrow) p1 = 0.0f;                                          \
        if (kb + 2 > qrow) p2 = 0.0f;                                          \
        if (kb + 3 > qrow) p3 = 0.0f;                                          \
      }                                                                        \
      uintx2 pk;                                                               \
      pk[0] = pkbf2(p0, p1);                                                   \
      pk[1] = pkbf2(p2, p3);                                                   \
      *(uintx2*)&QPs[(w * 16 + lm) * LD + j * 16 + quad * 4] = pk;             \
    }                                                                          \
    _Pragma("unroll")                                                          \
    for (int kk = 0; kk < 2; ++kk) {                                           \
      bf16x8 pf = *(const bf16x8*)&QPs[(w * 16 + lm) * LD + kk * 32 + quad * 8]; \
      _Pragma("unroll")                                                        \
      for (int j = 0; j < 4; ++j) {                                            \
        bf16x8 vf = *(const bf16x8*)&(VSc)[(j * 16 + lm) * LD + kk * 32 + quad * 8]; \
        o[j] = __builtin_amdgcn_mfma_f32_16x16x32_bf16(pf, vf, o[j], 0, 0, 0); \
      }                                                                        \
      l_acc = __builtin_amdgcn_mfma_f32_16x16x32_bf16(pf, ones, l_acc, 0, 0, 0); \
    }                                                                          \
    if (!(LAST)) __syncthreads();                                              \
  } while (0)

__global__ __launch_bounds__(256)
void attention(const unsigned short* __restrict__ qk,
               const unsigned short* __restrict__ Vt,
               unsigned short* __restrict__ Y)
{
    constexpr int LD = 72;
    __shared__ __align__(16) unsigned short QPs[64 * LD];  // Q stage, then P
    __shared__ __align__(16) unsigned short Ks0[64 * LD];
    __shared__ __align__(16) unsigned short Ks1[64 * LD];
    __shared__ __align__(16) unsigned short Vs0[64 * LD];
    __shared__ __align__(16) unsigned short Vs1[64 * LD];

    const int tid  = threadIdx.x;
    const int lane = tid & 63;
    const int w    = tid >> 6;
    const int quad = lane >> 4;
    const int lm   = lane & 15;

    const int bh = blockIdx.x;
    const int qt = 31 - blockIdx.y;      // longest first
    const int b  = bh >> 4, h = bh & 15;
    const int q0 = qt * 64;
    const int qrow = q0 + w * 16 + lm;   // this lane's q-row (S^T layout)

    const int r0 = tid >> 3, r1 = r0 + 32, pc = (tid & 7) * 8;
    const unsigned short* kp0 = qk + (size_t)b * 2048 * 2048 + 1024 + h * 64
                              + (size_t)r0 * 2048 + pc;
    const unsigned short* kp1 = kp0 + (size_t)32 * 2048;
    const unsigned short* vp0 = Vt + (size_t)bh * 64 * 2048 + (size_t)r0 * 2048 + pc;
    const unsigned short* vp1 = vp0 + (size_t)32 * 2048;

    // stage Q tile
    #pragma unroll
    for (int i = 0; i < 2; ++i) {
        int c = i * 256 + tid, row = c >> 3, col = (c & 7) * 8;
        *(ushortx8*)&QPs[row * LD + col] =
            *(const ushortx8*)&qk[((size_t)(b * 2048 + q0 + row)) * 2048 + h * 64 + col];
    }

    // tile 0 -> buf0 directly; prefetch tile 1 into regs
    ushortx8 kreg0 = *(const ushortx8*)kp0, kreg1 = *(const ushortx8*)kp1;
    ushortx8 vreg0 = *(const ushortx8*)vp0, vreg1 = *(const ushortx8*)vp1;
    kp0 += (size_t)64 * 2048; kp1 += (size_t)64 * 2048;
    vp0 += 64; vp1 += 64;
    *(ushortx8*)&Ks0[r0 * LD + pc] = kreg0;
    *(ushortx8*)&Ks0[r1 * LD + pc] = kreg1;
    *(ushortx8*)&Vs0[r0 * LD + pc] = vreg0;
    *(ushortx8*)&Vs0[r1 * LD + pc] = vreg1;
    if (qt >= 1) {
        kreg0 = *(const ushortx8*)kp0; kreg1 = *(const ushortx8*)kp1;
        vreg0 = *(const ushortx8*)vp0; vreg1 = *(const ushortx8*)vp1;
        kp0 += (size_t)64 * 2048; kp1 += (size_t)64 * 2048;
        vp0 += 64; vp1 += 64;
    }
    __syncthreads();                     // Q + tile0 visible

    bf16x8 qf[2];
    #pragma unroll
    for (int kk = 0; kk < 2; ++kk)
        qf[kk] = *(const bf16x8*)&QPs[(w * 16 + lm) * LD + kk * 32 + quad * 8];

    bf16x8 ones;
    #pragma unroll
    for (int i = 0; i < 8; ++i) ones[i] = (short)0x3F80;   // bf16 1.0

    floatx4 o[4] = {};
    floatx4 l_acc = {};                  // row-sums, same D-layout rows as o
    const float c1 = 0.125f * 1.44269504f;   // scale * log2(e)
    const float c2 = 8.0f   * 1.44269504f;   // static max 8

    // mask-free steps in pairs (buffer parity static: even kt -> buf0)
    int kt = 0;
    for (; kt + 1 < qt; kt += 2) {
        ATTN_STEP(Ks0, Vs0, Ks1, Vs1, kt,     false, false);
        ATTN_STEP(Ks1, Vs1, Ks0, Vs0, kt + 1, false, false);
    }
    if (kt < qt) {                       // kt even here; one more mask-free step
        ATTN_STEP(Ks0, Vs0, Ks1, Vs1, kt, false, false);
        // diagonal lives in buf1 (qt odd)
        ATTN_STEP(Ks1, Vs1, Ks0, Vs0, qt, true, true);
    } else {                             // kt == qt (qt even): diagonal in buf0
        ATTN_STEP(Ks0, Vs0, Ks1, Vs1, qt, true, true);
    }

    float rinv[4];
    #pragma unroll
    for (int r = 0; r < 4; ++r) rinv[r] = 1.0f / l_acc[r];

    #pragma unroll
    for (int j = 0; j < 4; ++j) {
        int colg = h * 64 + j * 16 + lm;
        #pragma unroll
        for (int r = 0; r < 4; ++r) {
            int rowg = q0 + w * 16 + quad * 4 + r;
            Y[((size_t)(b * 2048 + rowg)) * 1024 + colg] = f2bf(o[j][r] * rinv[r]);
        }
    }
}

// ---------------------------------------------------------------------------
extern "C" void kernel_launch(void* const* d_in, const int* in_sizes, int n_in,
                              void* d_out, int out_size, void* d_ws, size_t ws_size,
                              hipStream_t stream)
{
    const float* x      = (const float*)d_in[0];   // [2,2048,1024] fp32
    const float* w_attn = (const float*)d_in[1];   // [3072,1024] fp32
    const float* w_proj = (const float*)d_in[2];   // [1024,1024] fp32
    float* out = (float*)d_out;                    // [2,2048,1024] fp32

    // ws: qk 16.8MB | Vt 8.4MB | y 8.4MB | wpb 2.1MB  (35.7 MB total)
    unsigned short* qkbuf = (unsigned short*)d_ws;
    unsigned short* Vtb   = qkbuf + (size_t)4096 * 2048;
    unsigned short* y     = Vtb   + (size_t)32 * 64 * 2048;
    unsigned short* wpb   = y     + (size_t)4096 * 1024;
    // d_out doubles as pre-cast scratch for xb/wab (dead before proj writes):
    unsigned short* xb  = (unsigned short*)d_out;             // 8.4MB
    unsigned short* wab = xb + (size_t)4096 * 1024;           // 6.3MB

    dim3 blk(256);
    cast_inputs<<<dim3(1024), blk, 0, stream>>>(x, w_attn, w_proj, xb, wab, wpb);
    // qkv GEMM (8-phase 256^2) + fused rmsnorm/rope (q,k) + transposed V
    gemm_qkv_8ph<<<dim3(12, 16), dim3(512), 0, stream>>>(xb, wab, qkbuf, Vtb);
    attention<<<dim3(32, 32), blk, 0, stream>>>(qkbuf, Vtb, y);
    gemm_bt<false, 64, 64>
        <<<dim3(16, 32), blk, 0, stream>>>(y, wpb, nullptr, out, nullptr, 4096, 1024, 1024);
}

// Round 2
// 176.202 us; speedup vs baseline: 1.0530x; 1.0530x over previous
//
#include <hip/hip_runtime.h>
#include <cstdint>
#include <cstddef>

// CausalSelfAttention MI355X (gfx950). fp32 I/O, bf16 MFMA compute, fp32 accum.
// B=2, T=2048, C=1024, H=16, Dh=64.
// [cast f32->bf16 + device rope-table] -> [QKV gemm: 256x256 8-phase template
// (T1 XCD swizzle, FULL 3-bit XOR LDS swizzle, T3/T4 counted vmcnt, T5
// setprio) with FUSED rmsnorm+rope(table) epilogue on q/k and transposed V] ->
// [flash attention (unchanged)] -> [gemm proj (m97 structure, unchanged)].
// Round-6 lesson: NEVER dynamically index register arrays. All static here.

typedef short bf16x8 __attribute__((ext_vector_type(8)));
typedef float floatx4 __attribute__((ext_vector_type(4)));
typedef float floatx2 __attribute__((ext_vector_type(2)));
typedef unsigned short ushortx8 __attribute__((ext_vector_type(8)));
typedef unsigned short ushortx4 __attribute__((ext_vector_type(4)));
typedef unsigned int uintx2 __attribute__((ext_vector_type(2)));

#define DEVI __device__ __forceinline__

DEVI float bf2f(unsigned short u) {
    unsigned int x = ((unsigned int)u) << 16;
    return __builtin_bit_cast(float, x);
}
DEVI unsigned short f2bf(float f) {
    unsigned int u = __builtin_bit_cast(unsigned int, f);
    u += 0x7fffu + ((u >> 16) & 1u);   // RNE; finite values only
    return (unsigned short)(u >> 16);
}
// pack 2 fp32 -> 2 bf16 in one dword (round-half-up; inputs >= 0 here)
DEVI unsigned int pkbf2(float a, float b) {
    unsigned int ua = __builtin_bit_cast(unsigned int, a) + 0x8000u;
    unsigned int ub = __builtin_bit_cast(unsigned int, b) + 0x8000u;
    return __builtin_amdgcn_perm(ub, ua, 0x07060302);
}

// async global->LDS, 16B per lane; LDS dest = wave-uniform base + lane*16.
DEVI void glds16(const unsigned short* g, unsigned short* l) {
    __builtin_amdgcn_global_load_lds(
        (const __attribute__((address_space(1))) unsigned int*)g,
        (__attribute__((address_space(3))) unsigned int*)l, 16, 0, 0);
}

DEVI void cast8(unsigned short* dst, const float* src) {
    floatx4 a = *(const floatx4*)src;
    floatx4 b = *(const floatx4*)(src + 4);
    ushortx8 o;
    o[0] = f2bf(a[0]); o[1] = f2bf(a[1]); o[2] = f2bf(a[2]); o[3] = f2bf(a[3]);
    o[4] = f2bf(b[0]); o[5] = f2bf(b[1]); o[6] = f2bf(b[2]); o[7] = f2bf(b[3]);
    *(ushortx8*)dst = o;
}

// ---------------------------------------------------------------------------
__global__ __launch_bounds__(256)
void cast_inputs(const float* __restrict__ x, const float* __restrict__ wa,
                 const float* __restrict__ wp,
                 unsigned short* __restrict__ xb, unsigned short* __restrict__ wab,
                 unsigned short* __restrict__ wpb, float* __restrict__ ropetab)
{
    size_t g = (size_t)blockIdx.x * 256 + threadIdx.x;
    size_t stride = (size_t)gridDim.x * 256;
    for (size_t i = g; i < (4194304 / 8); i += stride) cast8(xb  + i * 8, x  + i * 8);
    for (size_t i = g; i < (3145728 / 8); i += stride) cast8(wab + i * 8, wa + i * 8);
    for (size_t i = g; i < (1048576 / 8); i += stride) cast8(wpb + i * 8, wp + i * 8);
    // rope table: [t=0..2047][f=0..31] -> (cos, sin) of t * 1e4^(-f/32).
    // Same __sincosf/__expf as the old in-epilogue path -> identical numerics.
    for (size_t i = g; i < 65536; i += stride) {
        int t = (int)(i >> 5), f = (int)(i & 31);
        float ang = (float)t * __expf(-(float)f * 0.28782313662425572f); // ln(1e4)/32
        float sn, cs;
        __sincosf(ang, &sn, &cs);
        ropetab[2 * i]     = cs;
        ropetab[2 * i + 1] = sn;
    }
}

// ---------------------------------------------------------------------------
// QKV GEMM, 8-phase 256^2 template. C[M=4096,N=3072] = A[M,1024] @ B[N,1024]^T.
// 512 threads = 8 waves (2 wm x 4 wn), per-wave 128x64 output, BK=64,
// double-buffered 128 KiB LDS.
// LDS swizzle (rule 21: both-sides-or-neither): glds dest LINEAR; global
// source col pre-permuted chunk^=(row&7); ds_read chunk^=(row&7). row&7 ==
// lm&7 for all fragment reads -> XOR is lane-constant (folds into base) and
// the 16-row b128 read hits each 4-bank group with exactly 2 lanes (free).
// Stage order per tile: B0,B1,B2,B3,A0,A2,A1,A3 (8 KiB units, 2 per phase).
// vmcnt(4) at Ph2 covers odd-A of CURRENT tile (read Ph3); vmcnt(2) at Ph4
// covers B+even-A of NEXT tile (read Ph1/Ph2). Never vmcnt(0) mid-loop.
// ---------------------------------------------------------------------------
__global__ __launch_bounds__(512, 2)
void gemm_qkv_8ph(const unsigned short* __restrict__ A,
                  const unsigned short* __restrict__ B,
                  const float* __restrict__ ropetab,
                  unsigned short* __restrict__ Cqk,
                  unsigned short* __restrict__ Vt)
{
    __shared__ __align__(16) unsigned short lds[2][2][256 * 64]; // [buf][A/B][..] 128KiB

    const int tid  = threadIdx.x;
    const int lane = tid & 63;
    const int w    = tid >> 6;         // 0..7
    const int wm   = w >> 2;           // 0..1 (output row half)
    const int wn   = w & 3;            // 0..3 (output col quarter = one head)
    const int quad = lane >> 4;
    const int lm   = lane & 15;

    // bijective XCD swizzle (192 blocks, 192 % 8 == 0)
    const int lin = blockIdx.y * 12 + blockIdx.x;
    const int s   = (lin & 7) * 24 + (lin >> 3);
    const int m0  = (s / 12) * 256;
    const int n0  = (s % 12) * 256;

    // staging geometry: one unit = 64 rows x 64 cols bf16 = 8KiB = 512 lanes x 16B
    // LDS dest linear (thread tid -> ushort tid*8 within unit); global source
    // column chunk pre-XORed with (row&7) so swizzled reads see global order.
    const int srow = tid >> 3;                                       // 0..63
    const int scol = (((tid & 7) ^ ((tid >> 3) & 7)) * 8);           // pre-swizzled
    const int ldst = w * 512;                                        // wave LDS base

#define STG_A(u, WBi, kq) glds16(&A[(size_t)(m0 + (u) * 64 + srow) * 1024 + (kq) + scol], \
                                 &lds[WBi][0][(u) * 4096 + ldst])
#define STG_B(u, WBi, kq) glds16(&B[(size_t)(n0 + (u) * 64 + srow) * 1024 + (kq) + scol], \
                                 &lds[WBi][1][(u) * 4096 + ldst])
// swizzled read of 16B chunk (kk*4+quad) of row rrow: chunk ^= (rrow & 7)
#define RD_A(RBi, rrow, kk) (*(const bf16x8*)&lds[RBi][0][(rrow) * 64 + ((((kk) * 4 + quad) ^ ((rrow) & 7)) * 8)])
#define RD_B(RBi, rrow, kk) (*(const bf16x8*)&lds[RBi][1][(rrow) * 64 + ((((kk) * 4 + quad) ^ ((rrow) & 7)) * 8)])

    floatx4 acc[8][4] = {};
    bf16x8 afr[4][2];   // current m-half fragments (reloaded Ph1/Ph3)
    bf16x8 bfr[4][2];   // all 4 n-fragments (j0,1 from Ph1; j2,3 from Ph2)

#define MQ(MB, JB)                                                              \
  do {                                                                          \
    _Pragma("unroll")                                                           \
    for (int kk = 0; kk < 2; ++kk)                                              \
      _Pragma("unroll")                                                         \
      for (int mi = 0; mi < 4; ++mi)                                            \
        _Pragma("unroll")                                                       \
        for (int j2 = 0; j2 < 2; ++j2)                                          \
          acc[(MB) + mi][(JB) + j2] = __builtin_amdgcn_mfma_f32_16x16x32_bf16(  \
              afr[mi][kk], bfr[(JB) + j2][kk], acc[(MB) + mi][(JB) + j2], 0, 0, 0); \
  } while (0)

#define TILE(RBi, WBi, KT, LASTF)                                               \
  do {                                                                          \
    const int kn = ((KT) + 1) * 64;                                             \
    /* ---- Phase 1: stage next B0,B1; read A-even + B(j0,1) ---- */            \
    if (!(LASTF)) { STG_B(0, WBi, kn); STG_B(1, WBi, kn); }                     \
    _Pragma("unroll")                                                           \
    for (int kk = 0; kk < 2; ++kk) {                                            \
      _Pragma("unroll")                                                         \
      for (int mi = 0; mi < 4; ++mi)                                            \
        afr[mi][kk] = RD_A(RBi, wm * 128 + mi * 16 + lm, kk);                   \
      _Pragma("unroll")                                                         \
      for (int j2 = 0; j2 < 2; ++j2)                                            \
        bfr[j2][kk] = RD_B(RBi, wn * 64 + j2 * 16 + lm, kk);                    \
    }                                                                           \
    asm volatile("s_waitcnt lgkmcnt(8)" ::: "memory");                          \
    __builtin_amdgcn_s_barrier();                                               \
    asm volatile("s_waitcnt lgkmcnt(0)" ::: "memory");                          \
    __builtin_amdgcn_s_setprio(1); MQ(0, 0); __builtin_amdgcn_s_setprio(0);     \
    __builtin_amdgcn_s_barrier();                                               \
    /* ---- Phase 2: stage next B2,B3; read B(j2,3); vmcnt(4) ---- */           \
    if (!(LASTF)) { STG_B(2, WBi, kn); STG_B(3, WBi, kn); }                     \
    _Pragma("unroll")                                                           \
    for (int kk = 0; kk < 2; ++kk)                                              \
      _Pragma("unroll")                                                         \
      for (int j2 = 0; j2 < 2; ++j2)                                            \
        bfr[2 + j2][kk] = RD_B(RBi, wn * 64 + (2 + j2) * 16 + lm, kk);          \
    if (!(LASTF)) { asm volatile("s_waitcnt vmcnt(4)" ::: "memory"); }          \
    else          { asm volatile("s_waitcnt vmcnt(0)" ::: "memory"); }          \
    __builtin_amdgcn_s_barrier();                                               \
    asm volatile("s_waitcnt lgkmcnt(0)" ::: "memory");                          \
    __builtin_amdgcn_s_setprio(1); MQ(0, 2); __builtin_amdgcn_s_setprio(0);     \
    __builtin_amdgcn_s_barrier();                                               \
    /* ---- Phase 3: stage next A0,A2; read A-odd ---- */                       \
    if (!(LASTF)) { STG_A(0, WBi, kn); STG_A(2, WBi, kn); }                     \
    _Pragma("unroll")                                                           \
    for (int kk = 0; kk < 2; ++kk)                                              \
      _Pragma("unroll")                                                         \
      for (int mi = 0; mi < 4; ++mi)                                            \
        afr[mi][kk] = RD_A(RBi, wm * 128 + 64 + mi * 16 + lm, kk);              \
    __builtin_amdgcn_s_barrier();                                               \
    asm volatile("s_waitcnt lgkmcnt(0)" ::: "memory");                          \
    __builtin_amdgcn_s_setprio(1); MQ(4, 2); __builtin_amdgcn_s_setprio(0);     \
    __builtin_amdgcn_s_barrier();                                               \
    /* ---- Phase 4: stage next A1,A3; no reads (reuse regs); vmcnt(2) ---- */  \
    if (!(LASTF)) { STG_A(1, WBi, kn); STG_A(3, WBi, kn);                       \
                    asm volatile("s_waitcnt vmcnt(2)" ::: "memory"); }          \
    __builtin_amdgcn_s_barrier();                                               \
    __builtin_amdgcn_s_setprio(1); MQ(4, 0); __builtin_amdgcn_s_setprio(0);     \
    __builtin_amdgcn_s_barrier();                                               \
  } while (0)

    // prologue: stage tile 0 fully (order B0..B3, A0, A2, A1, A3), counted wait
    STG_B(0, 0, 0); STG_B(1, 0, 0); STG_B(2, 0, 0); STG_B(3, 0, 0);
    STG_A(0, 0, 0); STG_A(2, 0, 0); STG_A(1, 0, 0); STG_A(3, 0, 0);
    asm volatile("s_waitcnt vmcnt(2)" ::: "memory");   // B0..B3,A0,A2 done; A1,A3 in flight
    __builtin_amdgcn_s_barrier();

    for (int kt = 0; kt < 14; kt += 2) {
        TILE(0, 1, kt, false);
        TILE(1, 0, kt + 1, false);
    }
    TILE(0, 1, 14, false);
    TILE(1, 0, 15, true);

    // -------- fused epilogue: RMSNorm + RoPE via precomputed table --------
    const bool is_v = (n0 + wn * 64) >= 2048;   // wave-uniform; one head per wave
    if (!is_v) {
        const floatx2* rtab = (const floatx2*)ropetab;
        #pragma unroll
        for (int mi = 0; mi < 8; ++mi) {
            float rn[4];
            #pragma unroll
            for (int r = 0; r < 4; ++r) {
                float ss = 0.0f;
                #pragma unroll
                for (int j = 0; j < 4; ++j) ss += acc[mi][j][r] * acc[mi][j][r];
                ss += __shfl_xor(ss, 1, 64);
                ss += __shfl_xor(ss, 2, 64);
                ss += __shfl_xor(ss, 4, 64);
                ss += __shfl_xor(ss, 8, 64);
                rn[r] = rsqrtf(ss * (1.0f / 64.0f) + 1.1920929e-07f);
            }
            #pragma unroll
            for (int r = 0; r < 4; ++r) {
                int row = m0 + wm * 128 + mi * 16 + quad * 4 + r;
                int t = row & 2047;
                floatx2 cs0 = rtab[t * 32 + lm];        // f = lm      (j=0,2)
                floatx2 cs1 = rtab[t * 32 + 16 + lm];   // f = 16+lm   (j=1,3)
                float g = rn[r];
                #pragma unroll
                for (int j = 0; j < 4; ++j) {
                    int d = j * 16 + lm;
                    float cs = (j & 1) ? cs1[0] : cs0[0];
                    float sn = (j & 1) ? cs1[1] : cs0[1];
                    float v  = acc[mi][j][r] * g;
                    float vp = acc[mi][j ^ 2][r] * g;          // partner d^32
                    float sgn = (d < 32) ? -1.0f : 1.0f;       // (-x2, x1)
                    Cqk[(size_t)row * 2048 + (n0 + wn * 64 + d)] =
                        f2bf(v * cs + sgn * vp * sn);
                }
            }
        }
    } else {
        #pragma unroll
        for (int mi = 0; mi < 8; ++mi)
            #pragma unroll
            for (int j = 0; j < 4; ++j) {
                int col  = n0 + wn * 64 + j * 16 + lm;
                int row0 = m0 + wm * 128 + mi * 16 + quad * 4;
                int bq = row0 >> 11, t0 = row0 & 2047;
                ushortx4 pk;
                #pragma unroll
                for (int r = 0; r < 4; ++r) pk[r] = f2bf(acc[mi][j][r]);
                *(ushortx4*)&Vt[((size_t)(bq * 1024 + (col - 2048))) * 2048 + t0] = pk;
            }
    }
#undef TILE
#undef MQ
#undef RD_A
#undef RD_B
#undef STG_A
#undef STG_B
}

// ---------------------------------------------------------------------------
// C[M,N] = A[M,K] @ B[N,K]^T, bf16 in, fp32 accum. m97 structure: 128xBN
// tile, BK in {32,64}, global_load_lds width=16 into UNPADDED LDS.
// (Used only for the proj GEMM, QKV_SPLIT=false.)
// ---------------------------------------------------------------------------
template <bool QKV_SPLIT, int BN, int BK>
__global__ __launch_bounds__(256)
void gemm_bt(const unsigned short* __restrict__ A, const unsigned short* __restrict__ B,
             unsigned short* __restrict__ Cqk, float* __restrict__ Cf,
             unsigned short* __restrict__ Vt, int M, int N, int K)
{
    constexpr int WCOLS = (BN == 128) ? 2 : 1;
    constexpr int WROWS = 4 / WCOLS;
    constexpr int MI    = 128 / (16 * WROWS);   // 4 (BN=128) or 2 (BN=64)
    constexpr int LPR   = BK / 8;               // lanes per LDS row (16B each)
    constexpr int RPI   = 64 / LPR;             // rows covered per glds16

    __shared__ __align__(16) unsigned short As[128 * BK];
    __shared__ __align__(16) unsigned short Bs[BN * BK];

    const int tid  = threadIdx.x;
    const int lane = tid & 63;
    const int w    = tid >> 6;
    const int wm   = w / WCOLS, wn = w % WCOLS;
    const int quad = lane >> 4;
    const int lm   = lane & 15;
    const int m0 = blockIdx.y * 128;
    const int n0 = blockIdx.x * BN;
    const int sr = lane / LPR;
    const int sc = (lane % LPR) * 8;

    floatx4 acc[MI][4] = {};

    for (int k0 = 0; k0 < K; k0 += BK) {
        __syncthreads();
        #pragma unroll
        for (int i = 0; i < 32 / RPI; ++i) {
            int r = w * 32 + i * RPI;
            glds16(&A[(size_t)(m0 + r + sr) * K + k0 + sc], &As[r * BK]);
        }
        #pragma unroll
        for (int i = 0; i < (BN / 4) / RPI; ++i) {
            int r = w * (BN / 4) + i * RPI;
            glds16(&B[(size_t)(n0 + r + sr) * K + k0 + sc], &Bs[r * BK]);
        }
        __syncthreads();

        #pragma unroll
        for (int kk = 0; kk < BK / 32; ++kk) {
            bf16x8 a[MI];
            #pragma unroll
            for (int i = 0; i < MI; ++i)
                a[i] = *(const bf16x8*)&As[(wm * (16 * MI) + i * 16 + lm) * BK + kk * 32 + quad * 8];
            #pragma unroll
            for (int j = 0; j < 4; ++j) {
                bf16x8 b = *(const bf16x8*)&Bs[(wn * 64 + j * 16 + lm) * BK + kk * 32 + quad * 8];
                #pragma unroll
                for (int i = 0; i < MI; ++i)
                    acc[i][j] = __builtin_amdgcn_mfma_f32_16x16x32_bf16(a[i], b, acc[i][j], 0, 0, 0);
            }
        }
    }

    if constexpr (QKV_SPLIT) {
        // (unused instantiation path retained for reference)
    } else {
        #pragma unroll
        for (int i = 0; i < MI; ++i)
            #pragma unroll
            for (int j = 0; j < 4; ++j) {
                int col  = n0 + wn * 64 + j * 16 + lm;
                int row0 = m0 + wm * (16 * MI) + i * 16 + quad * 4;
                #pragma unroll
                for (int r = 0; r < 4; ++r)
                    Cf[(size_t)(row0 + r) * N + col] = acc[i][j][r];
            }
    }
}

// ---------------------------------------------------------------------------
// Flash attention. Double-buffered K/V LDS, ONE __syncthreads per key-step,
// buffer parity statically unrolled (pair loop + remainder — zero dynamic
// indexing). Peeled diagonal step (masked, no staging, no trailing barrier).
// S^T via mfma(A=K, B=Q); P packed b64 to own LDS strip; row-sums via
// mfma(P, ones) in o's D-layout.
// ---------------------------------------------------------------------------
#define ATTN_STEP(KSc, VSc, KSn, VSn, KT, DG, LAST)                            \
  do {                                                                         \
    if (!(LAST)) {                                                             \
      *(ushortx8*)&(KSn)[r0 * LD + pc] = kreg0;                                \
      *(ushortx8*)&(KSn)[r1 * LD + pc] = kreg1;                                \
      *(ushortx8*)&(VSn)[r0 * LD + pc] = vreg0;                                \
      *(ushortx8*)&(VSn)[r1 * LD + pc] = vreg1;                                \
      if ((KT) + 2 <= qt) {                                                    \
        kreg0 = *(const ushortx8*)kp0; kreg1 = *(const ushortx8*)kp1;          \
        vreg0 = *(const ushortx8*)vp0; vreg1 = *(const ushortx8*)vp1;          \
        kp0 += (size_t)64 * 2048; kp1 += (size_t)64 * 2048;                    \
        vp0 += 64; vp1 += 64;                                                  \
      }                                                                        \
    }                                                                          \
    floatx4 sa[4] = {};                                                        \
    _Pragma("unroll")                                                          \
    for (int kk = 0; kk < 2; ++kk)                                             \
      _Pragma("unroll")                                                        \
      for (int j = 0; j < 4; ++j) {                                            \
        bf16x8 kf = *(const bf16x8*)&(KSc)[(j * 16 + lm) * LD + kk * 32 + quad * 8]; \
        sa[j] = __builtin_amdgcn_mfma_f32_16x16x32_bf16(kf, qf[kk], sa[j], 0, 0, 0); \
      }                                                                        \
    _Pragma("unroll")                                                          \
    for (int j = 0; j < 4; ++j) {                                              \
      float p0 = exp2f(sa[j][0] * c1 - c2);                                    \
      float p1 = exp2f(sa[j][1] * c1 - c2);                                    \
      float p2 = exp2f(sa[j][2] * c1 - c2);                                    \
      float p3 = exp2f(sa[j][3] * c1 - c2);                                    \
      if (DG) {                                                                \
        int kb = (KT) * 64 + j * 16 + quad * 4;                                \
        if (kb + 0 > qrow) p0 = 0.0f;                                          \
        if (kb + 1 > qrow) p1 = 0.0f;                                          \
        if (kb + 2 > qrow) p2 = 0.0f;                                          \
        if (kb + 3 > qrow) p3 = 0.0f;                                          \
      }                                                                        \
      uintx2 pk;                                                               \
      pk[0] = pkbf2(p0, p1);                                                   \
      pk[1] = pkbf2(p2, p3);                                                   \
      *(uintx2*)&QPs[(w * 16 + lm) * LD + j * 16 + quad * 4] = pk;             \
    }                                                                          \
    _Pragma("unroll")                                                          \
    for (int kk = 0; kk < 2; ++kk) {                                           \
      bf16x8 pf = *(const bf16x8*)&QPs[(w * 16 + lm) * LD + kk * 32 + quad * 8]; \
      _Pragma("unroll")                                                        \
      for (int j = 0; j < 4; ++j) {                                            \
        bf16x8 vf = *(const bf16x8*)&(VSc)[(j * 16 + lm) * LD + kk * 32 + quad * 8]; \
        o[j] = __builtin_amdgcn_mfma_f32_16x16x32_bf16(pf, vf, o[j], 0, 0, 0); \
      }                                                                        \
      l_acc = __builtin_amdgcn_mfma_f32_16x16x32_bf16(pf, ones, l_acc, 0, 0, 0); \
    }                                                                          \
    if (!(LAST)) __syncthreads();                                              \
  } while (0)

__global__ __launch_bounds__(256)
void attention(const unsigned short* __restrict__ qk,
               const unsigned short* __restrict__ Vt,
               unsigned short* __restrict__ Y)
{
    constexpr int LD = 72;
    __shared__ __align__(16) unsigned short QPs[64 * LD];  // Q stage, then P
    __shared__ __align__(16) unsigned short Ks0[64 * LD];
    __shared__ __align__(16) unsigned short Ks1[64 * LD];
    __shared__ __align__(16) unsigned short Vs0[64 * LD];
    __shared__ __align__(16) unsigned short Vs1[64 * LD];

    const int tid  = threadIdx.x;
    const int lane = tid & 63;
    const int w    = tid >> 6;
    const int quad = lane >> 4;
    const int lm   = lane & 15;

    const int bh = blockIdx.x;
    const int qt = 31 - blockIdx.y;      // longest first
    const int b  = bh >> 4, h = bh & 15;
    const int q0 = qt * 64;
    const int qrow = q0 + w * 16 + lm;   // this lane's q-row (S^T layout)

    const int r0 = tid >> 3, r1 = r0 + 32, pc = (tid & 7) * 8;
    const unsigned short* kp0 = qk + (size_t)b * 2048 * 2048 + 1024 + h * 64
                              + (size_t)r0 * 2048 + pc;
    const unsigned short* kp1 = kp0 + (size_t)32 * 2048;
    const unsigned short* vp0 = Vt + (size_t)bh * 64 * 2048 + (size_t)r0 * 2048 + pc;
    const unsigned short* vp1 = vp0 + (size_t)32 * 2048;

    // stage Q tile
    #pragma unroll
    for (int i = 0; i < 2; ++i) {
        int c = i * 256 + tid, row = c >> 3, col = (c & 7) * 8;
        *(ushortx8*)&QPs[row * LD + col] =
            *(const ushortx8*)&qk[((size_t)(b * 2048 + q0 + row)) * 2048 + h * 64 + col];
    }

    // tile 0 -> buf0 directly; prefetch tile 1 into regs
    ushortx8 kreg0 = *(const ushortx8*)kp0, kreg1 = *(const ushortx8*)kp1;
    ushortx8 vreg0 = *(const ushortx8*)vp0, vreg1 = *(const ushortx8*)vp1;
    kp0 += (size_t)64 * 2048; kp1 += (size_t)64 * 2048;
    vp0 += 64; vp1 += 64;
    *(ushortx8*)&Ks0[r0 * LD + pc] = kreg0;
    *(ushortx8*)&Ks0[r1 * LD + pc] = kreg1;
    *(ushortx8*)&Vs0[r0 * LD + pc] = vreg0;
    *(ushortx8*)&Vs0[r1 * LD + pc] = vreg1;
    if (qt >= 1) {
        kreg0 = *(const ushortx8*)kp0; kreg1 = *(const ushortx8*)kp1;
        vreg0 = *(const ushortx8*)vp0; vreg1 = *(const ushortx8*)vp1;
        kp0 += (size_t)64 * 2048; kp1 += (size_t)64 * 2048;
        vp0 += 64; vp1 += 64;
    }
    __syncthreads();                     // Q + tile0 visible

    bf16x8 qf[2];
    #pragma unroll
    for (int kk = 0; kk < 2; ++kk)
        qf[kk] = *(const bf16x8*)&QPs[(w * 16 + lm) * LD + kk * 32 + quad * 8];

    bf16x8 ones;
    #pragma unroll
    for (int i = 0; i < 8; ++i) ones[i] = (short)0x3F80;   // bf16 1.0

    floatx4 o[4] = {};
    floatx4 l_acc = {};                  // row-sums, same D-layout rows as o
    const float c1 = 0.125f * 1.44269504f;   // scale * log2(e)
    const float c2 = 8.0f   * 1.44269504f;   // static max 8

    // mask-free steps in pairs (buffer parity static: even kt -> buf0)
    int kt = 0;
    for (; kt + 1 < qt; kt += 2) {
        ATTN_STEP(Ks0, Vs0, Ks1, Vs1, kt,     false, false);
        ATTN_STEP(Ks1, Vs1, Ks0, Vs0, kt + 1, false, false);
    }
    if (kt < qt) {                       // kt even here; one more mask-free step
        ATTN_STEP(Ks0, Vs0, Ks1, Vs1, kt, false, false);
        // diagonal lives in buf1 (qt odd)
        ATTN_STEP(Ks1, Vs1, Ks0, Vs0, qt, true, true);
    } else {                             // kt == qt (qt even): diagonal in buf0
        ATTN_STEP(Ks0, Vs0, Ks1, Vs1, qt, true, true);
    }

    float rinv[4];
    #pragma unroll
    for (int r = 0; r < 4; ++r) rinv[r] = 1.0f / l_acc[r];

    #pragma unroll
    for (int j = 0; j < 4; ++j) {
        int colg = h * 64 + j * 16 + lm;
        #pragma unroll
        for (int r = 0; r < 4; ++r) {
            int rowg = q0 + w * 16 + quad * 4 + r;
            Y[((size_t)(b * 2048 + rowg)) * 1024 + colg] = f2bf(o[j][r] * rinv[r]);
        }
    }
}

// ---------------------------------------------------------------------------
extern "C" void kernel_launch(void* const* d_in, const int* in_sizes, int n_in,
                              void* d_out, int out_size, void* d_ws, size_t ws_size,
                              hipStream_t stream)
{
    const float* x      = (const float*)d_in[0];   // [2,2048,1024] fp32
    const float* w_attn = (const float*)d_in[1];   // [3072,1024] fp32
    const float* w_proj = (const float*)d_in[2];   // [1024,1024] fp32
    float* out = (float*)d_out;                    // [2,2048,1024] fp32

    // ws: qk 16.8MB | Vt 8.4MB | y 8.4MB | wpb 2.1MB  (35.7 MB total)
    unsigned short* qkbuf = (unsigned short*)d_ws;
    unsigned short* Vtb   = qkbuf + (size_t)4096 * 2048;
    unsigned short* y     = Vtb   + (size_t)32 * 64 * 2048;
    unsigned short* wpb   = y     + (size_t)4096 * 1024;
    // d_out doubles as pre-cast scratch (dead before proj writes):
    unsigned short* xb  = (unsigned short*)d_out;             // 8.4MB
    unsigned short* wab = xb + (size_t)4096 * 1024;           // 6.3MB
    float* ropetab = (float*)(wab + (size_t)3072 * 1024);     // 512KB (2048x32x2 f32)

    dim3 blk(256);
    cast_inputs<<<dim3(1024), blk, 0, stream>>>(x, w_attn, w_proj, xb, wab, wpb, ropetab);
    // qkv GEMM (8-phase 256^2) + fused rmsnorm/rope (q,k) + transposed V
    gemm_qkv_8ph<<<dim3(12, 16), dim3(512), 0, stream>>>(xb, wab, ropetab, qkbuf, Vtb);
    attention<<<dim3(32, 32), blk, 0, stream>>>(qkbuf, Vtb, y);
    gemm_bt<false, 64, 64>
        <<<dim3(16, 32), blk, 0, stream>>>(y, wpb, nullptr, out, nullptr, 4096, 1024, 1024);
}